// Round 1
// baseline (2288.249 us; speedup 1.0000x reference)
//
#include <hip/hip_runtime.h>
#include <math.h>

typedef unsigned short u16;
typedef unsigned int   u32;
typedef __attribute__((ext_vector_type(8))) short bf16x8;
typedef __attribute__((ext_vector_type(4))) float f32x4;

#define DEV static __device__ __forceinline__

DEV u16 f2b(float f) {
  union { float f; u32 u; } v; v.f = f;
  u32 r = v.u + 0x7FFFu + ((v.u >> 16) & 1u);
  return (u16)(r >> 16);
}
DEV float b2f(u16 h) {
  union { u32 u; float f; } v; v.u = ((u32)h) << 16;
  return v.f;
}
DEV float gelu_f(float x) { return 0.5f * x * (1.0f + erff(x * 0.70710678118654752f)); }

DEV void gload16(const u16* g, u16* l) {
  __builtin_amdgcn_global_load_lds(
      (const __attribute__((address_space(1))) void*)g,
      (__attribute__((address_space(3))) void*)l, 16, 0, 0);
}

// ---------------- weight transpose: fp32 (K,N) -> bf16 (N,K) ----------------
__global__ void k_transpose_w(const float* __restrict__ src, u16* __restrict__ dst,
                              int K, int N) {
  long t = (long)blockIdx.x * 256 + threadIdx.x;
  if (t >= (long)K * N) return;
  int n = (int)(t / K), k = (int)(t % K);
  dst[t] = f2b(src[(long)k * N + n]);
}

// ---------------- per-window uncertainty mean (numpy pairwise order) --------
__global__ void k_scores(const float* __restrict__ unc, float* __restrict__ scores) {
  int id = blockIdx.x * 256 + threadIdx.x;
  if (id >= 8192) return;
  int b = id >> 12, win = id & 4095;
  int h0 = (win >> 6) << 3, w0 = (win & 63) << 3;
  float r[8] = {0.f,0.f,0.f,0.f,0.f,0.f,0.f,0.f};
  for (int i = 0; i < 8; ++i) {
    long base = ((long)(b * 512 + h0 + i)) * 512 + w0;
    #pragma unroll
    for (int j = 0; j < 8; ++j) r[j] += unc[base + j];
  }
  float s = ((r[0] + r[1]) + (r[2] + r[3])) + ((r[4] + r[5]) + (r[6] + r[7]));
  scores[id] = s * (1.0f / 64.0f);
}

// ---------------- top-k (1228 of 4096) per batch: bitonic, tie -> lower idx --
__global__ __launch_bounds__(1024) void k_topk(
    const float* __restrict__ scores, int* __restrict__ row2win,
    int* __restrict__ win2row, int nWF) {
  __shared__ float ls[4096];
  __shared__ int   li[4096];
  const int b = blockIdx.x;
  const int tid = threadIdx.x;
  for (int i = tid; i < 4096; i += 1024) {
    ls[i] = scores[b * 4096 + i];
    li[i] = i;
    win2row[b * 4096 + i] = -1;
  }
  __syncthreads();
  for (int k = 2; k <= 4096; k <<= 1) {
    for (int j = k >> 1; j > 0; j >>= 1) {
      for (int t = tid; t < 2048; t += 1024) {
        int i = ((t / j) * (j << 1)) + (t % j);
        int ixj = i + j;
        bool up = ((i & k) == 0);
        float sa = ls[i], sb = ls[ixj];
        int ia = li[i], ib = li[ixj];
        bool g = (sa > sb) || (sa == sb && ia < ib);  // a ranks before b
        if (g != up) { ls[i] = sb; ls[ixj] = sa; li[i] = ib; li[ixj] = ia; }
      }
      __syncthreads();
    }
  }
  for (int r = tid; r < nWF; r += 1024) {
    int win = li[r];
    row2win[b * nWF + r] = (b << 12) | win;
    win2row[b * 4096 + win] = b * nWF + r;
  }
}

// ---------------- gather selected window + LayerNorm -> xn (bf16) ----------
__global__ __launch_bounds__(256) void k_gather_ln(
    const float* __restrict__ fm, const float* __restrict__ nw,
    const float* __restrict__ nb, const int* __restrict__ row2win,
    u16* __restrict__ xn, int winStart) {
  __shared__ float sx[64 * 256];   // [tok][c ^ ((tok&15)<<1)], 64 KiB
  const int tid = threadIdx.x;
  const int rw = row2win[winStart + blockIdx.x];
  const int b = rw >> 12, win = rw & 4095;
  const int h0 = (win >> 6) << 3, w0 = (win & 63) << 3;
  {
    const int c = tid;
    long base = ((long)(b * 256 + c) * 512 + h0) * 512 + w0;
    for (int i = 0; i < 8; ++i) {
      float4 v0 = *(const float4*)(fm + base + (long)i * 512);
      float4 v1 = *(const float4*)(fm + base + (long)i * 512 + 4);
      float vv[8] = {v0.x, v0.y, v0.z, v0.w, v1.x, v1.y, v1.z, v1.w};
      #pragma unroll
      for (int j = 0; j < 8; ++j) {
        int tok = i * 8 + j;
        sx[tok * 256 + (c ^ ((tok & 15) << 1))] = vv[j];
      }
    }
  }
  __syncthreads();
  const int tok = tid >> 2, g = tid & 3;
  const int swz = (tok & 15) << 1;
  float sum = 0.f;
  for (int q = 0; q < 64; ++q) sum += sx[tok * 256 + ((g * 64 + q) ^ swz)];
  sum += __shfl_xor(sum, 1);
  sum += __shfl_xor(sum, 2);
  const float mu = sum * (1.0f / 256.0f);
  float s2 = 0.f;
  for (int q = 0; q < 64; ++q) {
    float d = sx[tok * 256 + ((g * 64 + q) ^ swz)] - mu;
    s2 += d * d;
  }
  s2 += __shfl_xor(s2, 1);
  s2 += __shfl_xor(s2, 2);
  const float rs = rsqrtf(s2 * (1.0f / 256.0f) + 1e-5f);
  long obase = ((long)blockIdx.x * 64 + tok) * 256 + g * 64;
  for (int q8 = 0; q8 < 8; ++q8) {
    u16 tmp[8];
    #pragma unroll
    for (int e = 0; e < 8; ++e) {
      int c = g * 64 + q8 * 8 + e;
      float v = (sx[tok * 256 + (c ^ swz)] - mu) * rs * nw[c] + nb[c];
      tmp[e] = f2b(v);
    }
    *(ulonglong2*)(xn + obase + q8 * 8) = *(const ulonglong2*)tmp;
  }
}

// ---------------- GEMM: Y[M,N](bf16) = epi(A[M,K](bf16) @ Bt[N,K]^T) --------
// EPI 0: Y = acc ; EPI 1: Y = gelu(acc+bias) ; EPI 2: Y = Res + gelu(acc+bias)
template <int EPI>
__global__ __launch_bounds__(256) void k_gemm_bt(
    const u16* __restrict__ A, const u16* __restrict__ Bt,
    const float* __restrict__ bias, const u16* __restrict__ Res,
    u16* __restrict__ Y, int N, int K) {
  __shared__ __attribute__((aligned(16))) u16 sA[128 * 64];
  __shared__ __attribute__((aligned(16))) u16 sB[128 * 64];
  const int tid = threadIdx.x;
  const int l = tid & 63, w = tid >> 6;
  const int tm = blockIdx.x, tn = blockIdx.y;

  // staging map: lane l of wave w covers LDS bytes [w*1024 + l*16), rows of 64-wide bf16 tile,
  // source k pre-swizzled so LDS-linear dest == XOR-swizzled layout (rule #21).
  const int row0 = w * 8 + (l >> 3);
  const int k0 = ((((l & 7) << 4) ^ ((l >> 3) << 4)) >> 1);
  const u16* gA = A + (long)(tm * 128 + row0) * K + k0;
  const u16* gB = Bt + (long)(tn * 128 + row0) * K + k0;
  u16* lA = sA + w * 512 + l * 8;
  u16* lB = sB + w * 512 + l * 8;

  f32x4 acc[4][4] = {};
  const int wr = w >> 1, wc = w & 1;
  const int lr = l & 15;
  const int kbh = (l >> 4) << 4;

  const int nkt = K >> 6;
  for (int kt = 0; kt < nkt; ++kt) {
    #pragma unroll
    for (int it = 0; it < 4; ++it) {
      gload16(gA + (long)it * 32 * K + kt * 64, lA + it * 2048);
      gload16(gB + (long)it * 32 * K + kt * 64, lB + it * 2048);
    }
    __syncthreads();
    #pragma unroll
    for (int kk = 0; kk < 2; ++kk) {
      const int kb = kk * 64 + kbh;
      bf16x8 af[4], bv[4];
      #pragma unroll
      for (int mi = 0; mi < 4; ++mi) {
        int r = wr * 64 + mi * 16 + lr;
        af[mi] = *(const bf16x8*)((const char*)sA + r * 128 + (kb ^ ((r & 7) << 4)));
      }
      #pragma unroll
      for (int ni = 0; ni < 4; ++ni) {
        int r = wc * 64 + ni * 16 + lr;
        bv[ni] = *(const bf16x8*)((const char*)sB + r * 128 + (kb ^ ((r & 7) << 4)));
      }
      #pragma unroll
      for (int mi = 0; mi < 4; ++mi)
        #pragma unroll
        for (int ni = 0; ni < 4; ++ni)
          acc[mi][ni] =
              __builtin_amdgcn_mfma_f32_16x16x32_bf16(af[mi], bv[ni], acc[mi][ni], 0, 0, 0);
    }
    __syncthreads();
  }

  const int rbase = tm * 128 + wr * 64 + ((l >> 4) << 2);
  const int cbase = tn * 128 + wc * 64 + lr;
  #pragma unroll
  for (int mi = 0; mi < 4; ++mi) {
    #pragma unroll
    for (int r = 0; r < 4; ++r) {
      long m = rbase + mi * 16 + r;
      #pragma unroll
      for (int ni = 0; ni < 4; ++ni) {
        int n = cbase + ni * 16;
        float v = acc[mi][ni][r];
        if (EPI >= 1) v = gelu_f(v + bias[n]);
        if (EPI == 2) v += b2f(Res[m * N + n]);
        Y[m * N + n] = f2b(v);
      }
    }
  }
}

// ---------------- window attention: one block per (window, head) -----------
// qkv rows: token-major, 1536 = [q|k|v] x 8 heads x 64.  xf += softmax(qk^T*s) v
__global__ __launch_bounds__(256) void k_attn(
    const u16* __restrict__ qkv, u16* __restrict__ xf) {
  __shared__ __attribute__((aligned(16))) u16 sq[64 * 64];
  __shared__ __attribute__((aligned(16))) u16 sk[64 * 64];
  __shared__ __attribute__((aligned(16))) u16 sv[64 * 64];  // transposed: [d][t]
  __shared__ __attribute__((aligned(16))) u16 sp[64 * 64];
  const int tid = threadIdx.x;
  const int l = tid & 63, w = tid >> 6;
  const int wloc = blockIdx.x >> 3, h = blockIdx.x & 7;
  const long tokbase = (long)wloc * 64;

  #pragma unroll
  for (int cc = 0; cc < 2; ++cc) {
    int cid = tid * 2 + cc;
    int t = cid >> 3, d0 = (cid & 7) << 3;
    long gq = (tokbase + t) * 1536 + h * 64 + d0;
    ulonglong2 vq = *(const ulonglong2*)(qkv + gq);
    ulonglong2 vk = *(const ulonglong2*)(qkv + gq + 512);
    int sbyte = t * 128 + ((d0 * 2) ^ ((t & 7) << 4));
    *(ulonglong2*)((char*)sq + sbyte) = vq;
    *(ulonglong2*)((char*)sk + sbyte) = vk;
    u16 vv[8];
    *(ulonglong2*)vv = *(const ulonglong2*)(qkv + gq + 1024);
    #pragma unroll
    for (int e = 0; e < 8; ++e) {
      int r = d0 + e;
      *(u16*)((char*)sv + r * 128 + ((t * 2) ^ ((r & 7) << 4))) = vv[e];
    }
  }
  __syncthreads();

  // S = q k^T  (wave w owns S rows [16w,16w+16))
  f32x4 accs[4] = {};
  #pragma unroll
  for (int ks = 0; ks < 2; ++ks) {
    int kb = ks * 64 + ((l >> 4) << 4);
    int ra = w * 16 + (l & 15);
    bf16x8 aq = *(const bf16x8*)((char*)sq + ra * 128 + (kb ^ ((ra & 7) << 4)));
    #pragma unroll
    for (int cf = 0; cf < 4; ++cf) {
      int rb = cf * 16 + (l & 15);
      bf16x8 bk = *(const bf16x8*)((char*)sk + rb * 128 + (kb ^ ((rb & 7) << 4)));
      accs[cf] = __builtin_amdgcn_mfma_f32_16x16x32_bf16(aq, bk, accs[cf], 0, 0, 0);
    }
  }
  const float scale = 0.17677669529663687f;  // (C//HEADS)^-0.5 = 32^-0.5
  float pv[4][4];
  #pragma unroll
  for (int r = 0; r < 4; ++r) {
    float m = -1e30f;
    #pragma unroll
    for (int cf = 0; cf < 4; ++cf) {
      pv[cf][r] = accs[cf][r] * scale;
      m = fmaxf(m, pv[cf][r]);
    }
    for (int off = 1; off < 16; off <<= 1) m = fmaxf(m, __shfl_xor(m, off));
    float s = 0.f;
    #pragma unroll
    for (int cf = 0; cf < 4; ++cf) { pv[cf][r] = __expf(pv[cf][r] - m); s += pv[cf][r]; }
    for (int off = 1; off < 16; off <<= 1) s += __shfl_xor(s, off);
    float inv = 1.0f / s;
    #pragma unroll
    for (int cf = 0; cf < 4; ++cf) pv[cf][r] *= inv;
  }
  #pragma unroll
  for (int cf = 0; cf < 4; ++cf)
    #pragma unroll
    for (int r = 0; r < 4; ++r) {
      int pr = w * 16 + ((l >> 4) << 2) + r, pc = cf * 16 + (l & 15);
      *(u16*)((char*)sp + pr * 128 + ((pc * 2) ^ ((pr & 7) << 4))) = f2b(pv[cf][r]);
    }
  __syncthreads();

  // O = P v
  f32x4 acco[4] = {};
  #pragma unroll
  for (int ks = 0; ks < 2; ++ks) {
    int kb = ks * 64 + ((l >> 4) << 4);
    int ra = w * 16 + (l & 15);
    bf16x8 ap = *(const bf16x8*)((char*)sp + ra * 128 + (kb ^ ((ra & 7) << 4)));
    #pragma unroll
    for (int cf = 0; cf < 4; ++cf) {
      int rb = cf * 16 + (l & 15);
      bf16x8 bvv = *(const bf16x8*)((char*)sv + rb * 128 + (kb ^ ((rb & 7) << 4)));
      acco[cf] = __builtin_amdgcn_mfma_f32_16x16x32_bf16(ap, bvv, acco[cf], 0, 0, 0);
    }
  }
  #pragma unroll
  for (int cf = 0; cf < 4; ++cf)
    #pragma unroll
    for (int r = 0; r < 4; ++r) {
      long m = tokbase + w * 16 + ((l >> 4) << 2) + r;
      int n = h * 64 + cf * 16 + (l & 15);
      long idx = m * 512 + n;
      xf[idx] = f2b(acco[cf][r] + b2f(xf[idx]));
    }
}

// ---------------- final assemble: out = fm (+ out_f at selected windows) ---
__global__ __launch_bounds__(256) void k_assemble(
    const float* __restrict__ fm, const u16* __restrict__ out_f,
    const int* __restrict__ win2row, float* __restrict__ out) {
  __shared__ u16 so[2][64 * 256];
  const int tid = threadIdx.x;
  const int bq = blockIdx.x;  // ((b*64 + hw)*32 + wq)
  const int wq = bq & 31, hw = (bq >> 5) & 63, b = bq >> 11;
  const int win0 = hw * 64 + wq * 2;
  const int r0 = win2row[b * 4096 + win0];
  const int r1 = win2row[b * 4096 + win0 + 1];
  for (int s = 0; s < 2; ++s) {
    int row = s ? r1 : r0;
    if (row >= 0) {
      for (int it = 0; it < 8; ++it) {
        int cid = it * 256 + tid;
        *(ulonglong2*)(&so[s][cid * 8]) =
            *(const ulonglong2*)(out_f + (long)row * 16384 + cid * 8);
      }
    }
  }
  __syncthreads();
  const int c = tid;
  const int h0 = hw * 8, w0 = wq * 16;
  long base = ((long)(b * 256 + c) * 512 + h0) * 512 + w0;
  for (int i = 0; i < 8; ++i) {
    float4 v[4];
    #pragma unroll
    for (int p = 0; p < 4; ++p) v[p] = *(const float4*)(fm + base + (long)i * 512 + p * 4);
    float* vf = (float*)v;
    if (r0 >= 0) {
      #pragma unroll
      for (int j = 0; j < 8; ++j) vf[j] += b2f(so[0][(i * 8 + j) * 256 + c]);
    }
    if (r1 >= 0) {
      #pragma unroll
      for (int j = 0; j < 8; ++j) vf[j + 8] += b2f(so[1][(i * 8 + j) * 256 + c]);
    }
    #pragma unroll
    for (int p = 0; p < 4; ++p) *(float4*)(out + base + (long)i * 512 + p * 4) = v[p];
  }
}

// ============================ host launcher =================================
extern "C" void kernel_launch(void* const* d_in, const int* in_sizes, int n_in,
                              void* d_out, int out_size, void* d_ws, size_t ws_size,
                              hipStream_t stream) {
  const float* fm     = (const float*)d_in[0];
  const float* unc    = (const float*)d_in[1];
  const float* nw     = (const float*)d_in[2];
  const float* nb     = (const float*)d_in[3];
  const float* w_lin0 = (const float*)d_in[4];
  const float* b_lin0 = (const float*)d_in[5];
  const float* w_qkv0 = (const float*)d_in[6];
  const float* w_lin1 = (const float*)d_in[7];
  const float* b_lin1 = (const float*)d_in[8];
  const float* w_qkv1 = (const float*)d_in[9];
  const float* w_proj = (const float*)d_in[10];
  const float* b_proj = (const float*)d_in[11];
  float* out = (float*)d_out;

  const int nWF = 1228, totWin = 2456;
  const long totTok = (long)totWin * 64;

  char* p = (char*)d_ws;
  auto alloc = [&](size_t bytes) {
    char* r = p;
    p += (bytes + 255) & ~(size_t)255;
    return r;
  };
  float* scores = (float*)alloc(8192 * 4);
  int* win2row  = (int*)alloc(8192 * 4);
  int* row2win  = (int*)alloc(totWin * 4);
  u16* wT       = (u16*)alloc((size_t)2097152 * 2);
  u16* out_f    = (u16*)alloc((size_t)(totTok + 128) * 256 * 2);
  size_t persist = (size_t)(p - (char*)d_ws);

  int nChunks = 64, wpc = (totWin + 63) / 64;
  const int cand[7] = {1, 2, 4, 8, 16, 32, 64};
  for (int ci = 0; ci < 7; ++ci) {
    int n = cand[ci];
    int wp = (totWin + n - 1) / n;
    long mc = (((long)wp * 64 + 127) / 128) * 128;
    size_t need = persist + 4096 +
                  (((size_t)mc * 256 * 2 + 255) & ~(size_t)255) +
                  2 * (((size_t)mc * 512 * 2 + 255) & ~(size_t)255) +
                  (((size_t)mc * 1536 * 2 + 255) & ~(size_t)255);
    if (need <= ws_size) { nChunks = n; wpc = wp; break; }
  }
  long mcap = (((long)wpc * 64 + 127) / 128) * 128;
  u16* xn   = (u16*)alloc((size_t)mcap * 256 * 2);
  u16* xfa  = (u16*)alloc((size_t)mcap * 512 * 2);
  u16* xfb  = (u16*)alloc((size_t)mcap * 512 * 2);
  u16* qkvb = (u16*)alloc((size_t)mcap * 1536 * 2);

  u16* wT_lin0 = wT;
  u16* wT_qkv0 = wT + 131072;
  u16* wT_lin1 = wT + 917504;
  u16* wT_qkv1 = wT + 1179648;
  u16* wT_proj = wT + 1966080;
  k_transpose_w<<<(131072 + 255) / 256, 256, 0, stream>>>(w_lin0, wT_lin0, 256, 512);
  k_transpose_w<<<(786432 + 255) / 256, 256, 0, stream>>>(w_qkv0, wT_qkv0, 512, 1536);
  k_transpose_w<<<(262144 + 255) / 256, 256, 0, stream>>>(w_lin1, wT_lin1, 512, 512);
  k_transpose_w<<<(786432 + 255) / 256, 256, 0, stream>>>(w_qkv1, wT_qkv1, 512, 1536);
  k_transpose_w<<<(131072 + 255) / 256, 256, 0, stream>>>(w_proj, wT_proj, 512, 256);

  k_scores<<<32, 256, 0, stream>>>(unc, scores);
  k_topk<<<2, 1024, 0, stream>>>(scores, row2win, win2row, nWF);

  for (int c = 0; c < nChunks; ++c) {
    int w0 = c * wpc;
    if (w0 >= totWin) break;
    int rem = totWin - w0;
    int wn = (wpc < rem) ? wpc : rem;
    int mTiles = (int)(((long)wn * 64 + 127) / 128);
    k_gather_ln<<<wn, 256, 0, stream>>>(fm, nw, nb, row2win, xn, w0);
    k_gemm_bt<1><<<dim3(mTiles, 4), 256, 0, stream>>>(xn, wT_lin0, b_lin0, nullptr, xfa, 512, 256);
    k_gemm_bt<0><<<dim3(mTiles, 12), 256, 0, stream>>>(xfa, wT_qkv0, nullptr, nullptr, qkvb, 1536, 512);
    k_attn<<<wn * 8, 256, 0, stream>>>(qkvb, xfa);
    k_gemm_bt<2><<<dim3(mTiles, 4), 256, 0, stream>>>(xfa, wT_lin1, b_lin1, xfa, xfb, 512, 512);
    k_gemm_bt<0><<<dim3(mTiles, 12), 256, 0, stream>>>(xfb, wT_qkv1, nullptr, nullptr, qkvb, 1536, 512);
    k_attn<<<wn * 8, 256, 0, stream>>>(qkvb, xfb);
    k_gemm_bt<2><<<dim3(mTiles, 2), 256, 0, stream>>>(xfb, wT_proj, b_proj, xn,
                                                      out_f + (long)w0 * 64 * 256, 256, 512);
  }
  k_assemble<<<4096, 256, 0, stream>>>(fm, out_f, win2row, out);
}